// Round 1
// baseline (889.319 us; speedup 1.0000x reference)
//
#include <hip/hip_runtime.h>

typedef _Float16 half8 __attribute__((ext_vector_type(8)));
typedef _Float16 half4 __attribute__((ext_vector_type(4)));
typedef _Float16 half2v __attribute__((ext_vector_type(2)));
typedef float floatx4 __attribute__((ext_vector_type(4)));

__device__ __forceinline__ float fast_rcp(float x) { return __builtin_amdgcn_rcpf(x); }
__device__ __forceinline__ float fast_sigmoid(float x) {
  return fast_rcp(1.f + __expf(-x));
}
__device__ __forceinline__ float fast_tanh(float x) {
  return 1.f - 2.f * fast_rcp(1.f + __expf(2.f * x));
}

// ---------------- prep: fp16 fragment-ordered weights + bias sums ----------------
// B-frag layout for mfma_f32_16x16x32_f16: lane L, reg j holds
// W[n = ntile*16 + (L&15)][k = ktile*32 + (L>>4)*8 + j].
// Buffer: [ktile][ntile(32)][lane(64)][8 f16]. Verified correct rounds 1-8.
__global__ void prep_kernel(const float* __restrict__ wih0, const float* __restrict__ whh0,
                            const float* __restrict__ bih0, const float* __restrict__ bhh0,
                            const float* __restrict__ wih1, const float* __restrict__ whh1,
                            const float* __restrict__ bih1, const float* __restrict__ bhh1,
                            _Float16* __restrict__ w0f, _Float16* __restrict__ w1f,
                            float* __restrict__ bias0, float* __restrict__ bias1)
{
  int stride = gridDim.x * blockDim.x;
  int idx0 = blockIdx.x * blockDim.x + threadIdx.x;
  const int N0 = 6*32*64*8;      // layer0: K=192 (x 64 | h 128)
  const int N1 = 8*32*64*8;      // layer1: K=256 (h1 128 | h 128)
  for (int e = idx0; e < N0 + N1 + 1024; e += stride) {
    if (e < N0) {
      int j = e & 7; int le = e >> 3; int lane = le & 63; int frag = le >> 6;
      int kt = frag >> 5, ntile = frag & 31;
      int n = ntile*16 + (lane & 15);
      int kk = kt*32 + ((lane >> 4) << 3) + j;
      float v = (kk < 64) ? wih0[n*64 + kk] : whh0[n*128 + (kk - 64)];
      w0f[e] = (_Float16)v;
    } else if (e < N0 + N1) {
      int e2 = e - N0;
      int j = e2 & 7; int le = e2 >> 3; int lane = le & 63; int frag = le >> 6;
      int kt = frag >> 5, ntile = frag & 31;
      int n = ntile*16 + (lane & 15);
      int kk = kt*32 + ((lane >> 4) << 3) + j;
      float v = (kk < 128) ? wih1[n*128 + kk] : whh1[n*128 + (kk - 128)];
      w1f[e2] = (_Float16)v;
    } else {
      int i = e - (N0 + N1);
      if (i < 512) bias0[i] = bih0[i] + bhh0[i];
      else         bias1[i - 512] = bih1[i - 512] + bhh1[i - 512];
    }
  }
}

// ---------------- fused 2-layer LSTM + linear head ----------------
// Phase p (0..527): l0 runs step t0 = p (p<512); l1 runs step t1 = p-16 (p>=16).
// l0 input projection: batched 8 steps (M=16), double-buffered pre0, as before.
// l1 input projection: batched 8 steps from the h0 hist ring (16-slot, written by
//   l0's epilogue), computed at phase 8*(bb+1) for batch bb (h0 steps 8bb..8bb+7
//   complete by phase 8bb+7; barrier-ordered), into pre1[bb&1]; consumed at phases
//   8bb+16..8bb+23. Slot reuse is barrier-separated (next write at 8bb+24).
// Recurrent weights (4 ktiles x 4 g per layer) resident in AGPRs (128 regs).
// Projection weights (l0 kt0..1, l1 kt0..3) are re-loaded from global (L2-resident,
//   same frags every batch) inside the per-8-phase projection block; an opaque
//   pointer asm stops LICM from hoisting 24 half8 loads into the loop-carried set.
__global__ __launch_bounds__(512, 2) void lstm_fused(const float* __restrict__ x,
    const _Float16* __restrict__ w0f, const float* __restrict__ bias0,
    const _Float16* __restrict__ w1f, const float* __restrict__ bias1,
    const float* __restrict__ wlin, const float* __restrict__ blin,
    float* __restrict__ out)
{
  const int tid = threadIdx.x;
  const int lane = tid & 63;
  const int w = tid >> 6;
  const int r0 = blockIdx.x * 2;

  __shared__ float pre0[2][8192];         // 64 KB: l0 pre-activations (8 steps x 2 rows)
  __shared__ float pre1[2][8192];         // 64 KB: l1 pre-activations
  __shared__ half8 aF[2][2*64];           // x A-frags, 2 ktiles (K=64), 4 KB
  __shared__ half8 hA0[2][4*8];           // compact recurrent frags l0 (1 KB)
  __shared__ half8 hA1[2][4*8];           // compact recurrent frags l1 (1 KB)
  __shared__ _Float16 hist[16][2][128];   // h0 history ring (8 KB) -> feeds l1 proj
  __shared__ float head[256];

  if (tid < 256) { ((int*)hA0)[tid] = 0; ((int*)hA1)[tid] = 0; }

  // resident recurrent weights: l0 kt2..5, l1 kt4..7
  half8 bf0r[4][4], bf1r[4][4];           // 32 frags = 128 AGPRs
#pragma unroll
  for (int kt = 0; kt < 4; ++kt)
#pragma unroll
    for (int g = 0; g < 4; ++g) {
      bf0r[kt][g] = *reinterpret_cast<const half8*>(w0f + (size_t)(((kt+2)*32 + g*8 + w)*64 + lane)*8);
      asm volatile("" : "+a"(bf0r[kt][g]));
      bf1r[kt][g] = *reinterpret_cast<const half8*>(w1f + (size_t)(((kt+4)*32 + g*8 + w)*64 + lane)*8);
      asm volatile("" : "+a"(bf1r[kt][g]));
    }
  float b0v[4], b1v[4];
#pragma unroll
  for (int g = 0; g < 4; ++g) {
    b0v[g] = bias0[g*128 + w*16 + (lane & 15)];
    b1v[g] = bias1[g*128 + w*16 + (lane & 15)];
  }

  // x staging: thread -> (dt, r, col-pair); full A-frag half index
  const int sdt = tid >> 6, sr = (tid >> 5) & 1, scp = (tid & 31) * 2;
  const int sm = sdt*2 + sr;
  const int sidx = ((scp>>5)*64 + sm + (((scp&31)>>3)<<4))*8 + (scp & 7);

  const bool arow = (lane & 11) == 0;
  const int cIdx = ((lane >> 4) << 1) | ((lane >> 2) & 1);
  const int rb = lane >> 4;
  const int en = w*16 + (lane & 15);
  const int eoff = ((en>>5)*8 + ((en&31)>>3)*2 + rb)*8 + (en&7);
  const float wl = (lane < 32) ? wlin[en] : 0.f;
  float cst0 = 0.f, cst1 = 0.f, hl = 0.f;

  // l1-proj A addressing into hist: lane L holds A[m=L&15][k=(L>>4)*8+j+kt*32],
  // m = dt*2 + r  ->  step = 8*bb + dt, row = r.
  const int dtL = (lane & 15) >> 1;
  const int rL  = lane & 1;
  const int kbase = (lane >> 4) * 8;

  // prologue: stage x batches 0 and 1
  {
    float2 v0 = *reinterpret_cast<const float2*>(x + ((size_t)(r0+sr)*512 + sdt)*64 + scp);
    float2 v1 = *reinterpret_cast<const float2*>(x + ((size_t)(r0+sr)*512 + 8 + sdt)*64 + scp);
    half2v h0; h0[0] = (_Float16)v0.x; h0[1] = (_Float16)v0.y;
    half2v h1v; h1v[0] = (_Float16)v1.x; h1v[1] = (_Float16)v1.y;
    *reinterpret_cast<half2v*>(((_Float16*)aF[0]) + sidx) = h0;
    *reinterpret_cast<half2v*>(((_Float16*)aF[1]) + sidx) = h1v;
  }
  __syncthreads();
  {                                        // l0 pre[batch0] -> pre0[0]
    floatx4 accP[4];
#pragma unroll
    for (int g = 0; g < 4; ++g) { float bb = b0v[g]; accP[g] = (floatx4){bb,bb,bb,bb}; }
#pragma unroll
    for (int kt = 0; kt < 2; ++kt) {
      half8 af = aF[0][kt*64 + lane];
#pragma unroll
      for (int g = 0; g < 4; ++g) {
        half8 wf = *reinterpret_cast<const half8*>(w0f + (size_t)((kt*32 + g*8 + w)*64 + lane)*8);
        accP[g] = __builtin_amdgcn_mfma_f32_16x16x32_f16(af, wf, accP[g], 0, 0, 0);
      }
    }
#pragma unroll
    for (int reg = 0; reg < 4; ++reg) {
      int m = ((lane>>4)<<2) + reg;
      floatx4 pv = (floatx4){accP[0][reg], accP[1][reg], accP[2][reg], accP[3][reg]};
      *reinterpret_cast<floatx4*>(&pre0[0][(m*128 + en)*4]) = pv;
    }
  }
  __syncthreads();

  half8 a00 = {}, a01 = {}, a02 = {}, a03 = {};   // l0 recurrent A-frags
  half8 a10 = {}, a11 = {}, a12 = {}, a13 = {};   // l1 recurrent A-frags

  for (int p = 0; p < 528; ++p) {
    const int b = p >> 3;
    if ((p & 7) == 0 && b < 62) {          // stage x batch b+2 -> aF[b&1]
      int s = (b+2)*8 + sdt;
      float2 v = *reinterpret_cast<const float2*>(x + ((size_t)(r0+sr)*512 + s)*64 + scp);
      half2v hv; hv[0] = (_Float16)v.x; hv[1] = (_Float16)v.y;
      *reinterpret_cast<half2v*>(((_Float16*)aF[b&1]) + sidx) = hv;
    }
    __syncthreads();

    if ((p & 7) == 0) {
      const _Float16* w0p = w0f; asm volatile("" : "+v"(w0p));
      const _Float16* w1p = w1f; asm volatile("" : "+v"(w1p));
      if (b < 63) {                        // l0 pre[batch b+1] -> pre0[(b+1)&1]
        int slot = (b+1) & 1;
        floatx4 accP[4];
#pragma unroll
        for (int g = 0; g < 4; ++g) { float bb2 = b0v[g]; accP[g] = (floatx4){bb2,bb2,bb2,bb2}; }
#pragma unroll
        for (int kt = 0; kt < 2; ++kt) {
          half8 af = aF[slot][kt*64 + lane];
#pragma unroll
          for (int g = 0; g < 4; ++g) {
            half8 wf = *reinterpret_cast<const half8*>(w0p + (size_t)((kt*32 + g*8 + w)*64 + lane)*8);
            accP[g] = __builtin_amdgcn_mfma_f32_16x16x32_f16(af, wf, accP[g], 0, 0, 0);
          }
        }
#pragma unroll
        for (int reg = 0; reg < 4; ++reg) {
          int m = ((lane>>4)<<2) + reg;
          floatx4 pv = (floatx4){accP[0][reg], accP[1][reg], accP[2][reg], accP[3][reg]};
          *reinterpret_cast<floatx4*>(&pre0[slot][(m*128 + en)*4]) = pv;
        }
      }
      int bb = b - 1;
      if (bb >= 0 && bb < 64) {            // l1 pre[batch bb] -> pre1[bb&1] from hist
        int slot = bb & 1;
        const _Float16* hrow = &hist[(bb & 1)*8 + dtL][rL][kbase];
        floatx4 accP[4];
#pragma unroll
        for (int g = 0; g < 4; ++g) { float bb2 = b1v[g]; accP[g] = (floatx4){bb2,bb2,bb2,bb2}; }
#pragma unroll
        for (int kt = 0; kt < 4; ++kt) {
          half8 af = *reinterpret_cast<const half8*>(hrow + kt*32);
#pragma unroll
          for (int g = 0; g < 4; ++g) {
            half8 wf = *reinterpret_cast<const half8*>(w1p + (size_t)((kt*32 + g*8 + w)*64 + lane)*8);
            accP[g] = __builtin_amdgcn_mfma_f32_16x16x32_f16(af, wf, accP[g], 0, 0, 0);
          }
        }
#pragma unroll
        for (int reg = 0; reg < 4; ++reg) {
          int m = ((lane>>4)<<2) + reg;
          floatx4 pv = (floatx4){accP[0][reg], accP[1][reg], accP[2][reg], accP[3][reg]};
          *reinterpret_cast<floatx4*>(&pre1[slot][(m*128 + en)*4]) = pv;
        }
      }
    }

    // ---------------- l0 step t0 = p ----------------
    if (p < 512) {
      floatx4 p4 = (floatx4){0.f, 0.f, 0.f, 0.f};
      if (lane < 32) {
        int mstep = ((p & 7) << 1) + rb;
        p4 = *reinterpret_cast<const floatx4*>(&pre0[b & 1][(mstep*128 + en)*4]);
      }
      floatx4 acc[4];
#pragma unroll
      for (int g = 0; g < 4; ++g) acc[g] = (floatx4){p4[g], 0.f, 0.f, 0.f};

      const int cur = p & 1;
      if (arow) {
        a00 = hA0[cur][0*8 + cIdx];
        a01 = hA0[cur][1*8 + cIdx];
        a02 = hA0[cur][2*8 + cIdx];
        a03 = hA0[cur][3*8 + cIdx];
      }
#pragma unroll
      for (int g = 0; g < 4; ++g)
        acc[g] = __builtin_amdgcn_mfma_f32_16x16x32_f16(a00, bf0r[0][g], acc[g], 0, 0, 0);
#pragma unroll
      for (int g = 0; g < 4; ++g)
        acc[g] = __builtin_amdgcn_mfma_f32_16x16x32_f16(a01, bf0r[1][g], acc[g], 0, 0, 0);
#pragma unroll
      for (int g = 0; g < 4; ++g)
        acc[g] = __builtin_amdgcn_mfma_f32_16x16x32_f16(a02, bf0r[2][g], acc[g], 0, 0, 0);
#pragma unroll
      for (int g = 0; g < 4; ++g)
        acc[g] = __builtin_amdgcn_mfma_f32_16x16x32_f16(a03, bf0r[3][g], acc[g], 0, 0, 0);

      if (lane < 32) {
        float ii = fast_sigmoid(acc[0][0]);
        float ff = fast_sigmoid(acc[1][0]);
        float gg = fast_tanh(acc[2][0]);
        float oo = fast_sigmoid(acc[3][0]);
        cst0 = ff*cst0 + ii*gg;
        float hv2 = oo*fast_tanh(cst0);
        _Float16 hh = (_Float16)hv2;
        ((_Float16*)hA0[cur^1])[eoff] = hh;
        hist[p & 15][rb][en] = hh;
      }
    }

    // ---------------- l1 step t1 = p - 16 ----------------
    if (p >= 16) {
      const int t1 = p - 16;
      const int b1 = t1 >> 3;
      floatx4 p4 = (floatx4){0.f, 0.f, 0.f, 0.f};
      if (lane < 32) {
        int mstep = ((t1 & 7) << 1) + rb;
        p4 = *reinterpret_cast<const floatx4*>(&pre1[b1 & 1][(mstep*128 + en)*4]);
      }
      floatx4 acc[4];
#pragma unroll
      for (int g = 0; g < 4; ++g) acc[g] = (floatx4){p4[g], 0.f, 0.f, 0.f};

      const int cur = t1 & 1;
      if (arow) {
        a10 = hA1[cur][0*8 + cIdx];
        a11 = hA1[cur][1*8 + cIdx];
        a12 = hA1[cur][2*8 + cIdx];
        a13 = hA1[cur][3*8 + cIdx];
      }
#pragma unroll
      for (int g = 0; g < 4; ++g)
        acc[g] = __builtin_amdgcn_mfma_f32_16x16x32_f16(a10, bf1r[0][g], acc[g], 0, 0, 0);
#pragma unroll
      for (int g = 0; g < 4; ++g)
        acc[g] = __builtin_amdgcn_mfma_f32_16x16x32_f16(a11, bf1r[1][g], acc[g], 0, 0, 0);
#pragma unroll
      for (int g = 0; g < 4; ++g)
        acc[g] = __builtin_amdgcn_mfma_f32_16x16x32_f16(a12, bf1r[2][g], acc[g], 0, 0, 0);
#pragma unroll
      for (int g = 0; g < 4; ++g)
        acc[g] = __builtin_amdgcn_mfma_f32_16x16x32_f16(a13, bf1r[3][g], acc[g], 0, 0, 0);

      if (lane < 32) {
        float ii = fast_sigmoid(acc[0][0]);
        float ff = fast_sigmoid(acc[1][0]);
        float gg = fast_tanh(acc[2][0]);
        float oo = fast_sigmoid(acc[3][0]);
        cst1 = ff*cst1 + ii*gg;
        hl = oo*fast_tanh(cst1);
        ((_Float16*)hA1[cur^1])[eoff] = (_Float16)hl;
      }
    }
  }

  // fused head: out[r] = sum_n h_last[r][n]*wlin[n] + blin
  if (lane < 32) head[rb*128 + en] = hl * wl;
  __syncthreads();
  if (tid < 2) {
    float s = blin[0];
    for (int n = 0; n < 128; ++n) s += head[tid*128 + n];
    out[r0 + tid] = s;
  }
}

extern "C" void kernel_launch(void* const* d_in, const int* in_sizes, int n_in,
                              void* d_out, int out_size, void* d_ws, size_t ws_size,
                              hipStream_t stream)
{
  const float* x    = (const float*)d_in[0];
  const float* wih0 = (const float*)d_in[1];
  const float* whh0 = (const float*)d_in[2];
  const float* bih0 = (const float*)d_in[3];
  const float* bhh0 = (const float*)d_in[4];
  const float* wih1 = (const float*)d_in[5];
  const float* whh1 = (const float*)d_in[6];
  const float* bih1 = (const float*)d_in[7];
  const float* bhh1 = (const float*)d_in[8];
  const float* wlin = (const float*)d_in[9];
  const float* blin = (const float*)d_in[10];
  float* out = (float*)d_out;

  char* ws = (char*)d_ws;
  _Float16* w0f = (_Float16*)(ws);               // 196608 B
  _Float16* w1f = (_Float16*)(ws + 196608);      // 262144 B
  float* bias0  = (float*)(ws + 458752);         // 2048 B
  float* bias1  = (float*)(ws + 460800);         // 2048 B

  prep_kernel<<<256, 256, 0, stream>>>(wih0, whh0, bih0, bhh0, wih1, whh1, bih1, bhh1,
                                       w0f, w1f, bias0, bias1);
  lstm_fused<<<256, 512, 0, stream>>>(x, w0f, bias0, w1f, bias1, wlin, blin, out);
}